// Round 14
// baseline (390.496 us; speedup 1.0000x reference)
//
#include <hip/hip_runtime.h>

#define N_NODES 100000
#define N_EDGES 3200000
#define D 128

#define K1C    391        // coarse buckets: bucket = dst >> 8 (256 nodes each)
#define CHUNK  4096       // edges per partition block (multiple of 4)
#define NCHUNK 782        // ceil(N_EDGES / CHUNK); last block cnt=1024 (mult of 4)
#define GEMMB  782        // gemm tiles (128 rows each)
#define CAPB   8960       // arena capacity per bucket (mean 8192, +8.5 sigma; EVEN)

// ---------------------------------------------------------------------------
// Workspace layout (bytes). ws >= 78,000,512 proven. Bucket arenas: bucket b's
// records live at [b*CAPB, b*CAPB + cnt[b]) — bases arithmetic. nodecnt+gcur
// contiguous so ONE memset zeroes both.
// ---------------------------------------------------------------------------
static const size_t OFF_SB    = 0;           // S bf16 packed: N*64 uints = 25.6 MB
static const size_t OFF_REC   = 25600000;    // K1C*CAPB int2  = 28.03 MB
static const size_t OFF_SORT2 = 53626880;    // K1C*CAPB uint  = 14.01 MB
static const size_t OFF_OFFS  = 67640320;    // N ints
static const size_t OFF_CNTS  = 68040320;    // nodecnt[N_NODES] + gcur[K1C]

typedef __attribute__((ext_vector_type(8))) short bf16x8;
typedef __attribute__((ext_vector_type(4))) float f32x4;

__device__ __forceinline__ unsigned short f2bf(float f) {
    unsigned u = __float_as_uint(f);
    return (unsigned short)((u + 0x7FFFu + ((u >> 16) & 1u)) >> 16);   // RNE
}

// ---------------------------------------------------------------------------
// FUSED kernel (512 threads): blocks [0,NCHUNK) run the LDS-staged coarse
// partition with REGISTER-CARRIED edges (each thread owns <=8 edges = 2 int4
// groups, loaded ONCE — pass 2 has zero global-load exposure) and emits
// fire-and-forget per-node count atomics (removes fine_sort's histogram
// pass); blocks [NCHUNK,NCHUNK+GEMMB) run the MFMA gemm (verbatim R12/13).
// ---------------------------------------------------------------------------
__global__ __launch_bounds__(512) void part_and_gemm(
        const int* __restrict__ esrc,
        const int* __restrict__ edst,
        const float* __restrict__ eval,
        int* __restrict__ nodecnt,
        int* __restrict__ gcursor,
        int2* __restrict__ rec_out,
        const float* __restrict__ X,
        const float* __restrict__ W,
        unsigned* __restrict__ Sb) {
    __shared__ __align__(16) union {
        unsigned short wfrag[8][4][64][8];   // gemm phase 1: 32 KB
        unsigned       stage[8][16][68];     // gemm phase 2: 34.8 KB
        struct {
            int2 staged[CHUNK];              // 32 KB
            unsigned short bkt[CHUNK];       // 8 KB
            int hist[K1C];
            int lofs[K1C];
            int gbase[K1C];
            int cur[K1C];
            int wsum[8];
        } p;                                 // partition: ~46.6 KB
    } u;

    const int t    = threadIdx.x;
    const int lane = t & 63;
    const int wave = t >> 6;

    if (blockIdx.x < NCHUNK) {
        // ------------- partition branch (register-carried edges) -----------
        const int e0  = blockIdx.x * CHUNK;
        const int cnt = min(CHUNK, N_EDGES - e0);   // 4096 or 1024, %4 == 0
        const int nq  = cnt >> 2;                   // 1024 or 256 int4 groups

        // load owned edges ONCE (static names — no runtime-indexed arrays)
        const bool hasA = (t < nq);
        const bool hasB = (t + 512 < nq);
        int4 d4a, s4a; float4 v4a;
        int4 d4b, s4b; float4 v4b;
        if (hasA) {
            d4a = ((const int4*)(edst + e0))[t];
            s4a = ((const int4*)(esrc + e0))[t];
            v4a = ((const float4*)(eval + e0))[t];
        }
        if (hasB) {
            d4b = ((const int4*)(edst + e0))[t + 512];
            s4b = ((const int4*)(esrc + e0))[t + 512];
            v4b = ((const float4*)(eval + e0))[t + 512];
        }

        for (int i = t; i < K1C; i += 512) u.p.hist[i] = 0;
        __syncthreads();

        // pass 1: LDS histogram + fire-and-forget global per-node counts
        if (hasA) {
            atomicAdd(&u.p.hist[d4a.x >> 8], 1);
            atomicAdd(&u.p.hist[d4a.y >> 8], 1);
            atomicAdd(&u.p.hist[d4a.z >> 8], 1);
            atomicAdd(&u.p.hist[d4a.w >> 8], 1);
            atomicAdd(&nodecnt[d4a.x], 1);
            atomicAdd(&nodecnt[d4a.y], 1);
            atomicAdd(&nodecnt[d4a.z], 1);
            atomicAdd(&nodecnt[d4a.w], 1);
        }
        if (hasB) {
            atomicAdd(&u.p.hist[d4b.x >> 8], 1);
            atomicAdd(&u.p.hist[d4b.y >> 8], 1);
            atomicAdd(&u.p.hist[d4b.z >> 8], 1);
            atomicAdd(&u.p.hist[d4b.w >> 8], 1);
            atomicAdd(&nodecnt[d4b.x], 1);
            atomicAdd(&nodecnt[d4b.y], 1);
            atomicAdd(&nodecnt[d4b.z], 1);
            atomicAdd(&nodecnt[d4b.w], 1);
        }
        __syncthreads();

        // scan K1C entries: per-wave shfl_up scan + cross-wave combine
        int hv   = (t < K1C) ? u.p.hist[t] : 0;
        int incl = hv;
        for (int off = 1; off < 64; off <<= 1) {
            int uu = __shfl_up(incl, off);
            if (lane >= off) incl += uu;
        }
        if (lane == 63) u.p.wsum[wave] = incl;
        __syncthreads();
        {
            int pre = 0;
            for (int w = 0; w < wave; ++w) pre += u.p.wsum[w];
            if (t < K1C) {
                int excl = pre + incl - hv;
                u.p.lofs[t]  = excl;
                u.p.cur[t]   = excl;
                u.p.gbase[t] = hv ? (t * CAPB + atomicAdd(&gcursor[t], hv)) : 0;
            }
        }
        __syncthreads();

        // pass 2: scatter from registers into LDS staging (no global loads)
        if (hasA) {
            {
                int b = d4a.x >> 8;
                int pos = atomicAdd(&u.p.cur[b], 1);
                u.p.staged[pos] = make_int2(s4a.x | ((d4a.x & 255) << 17),
                                            __float_as_int(v4a.x));
                u.p.bkt[pos] = (unsigned short)b;
            }
            {
                int b = d4a.y >> 8;
                int pos = atomicAdd(&u.p.cur[b], 1);
                u.p.staged[pos] = make_int2(s4a.y | ((d4a.y & 255) << 17),
                                            __float_as_int(v4a.y));
                u.p.bkt[pos] = (unsigned short)b;
            }
            {
                int b = d4a.z >> 8;
                int pos = atomicAdd(&u.p.cur[b], 1);
                u.p.staged[pos] = make_int2(s4a.z | ((d4a.z & 255) << 17),
                                            __float_as_int(v4a.z));
                u.p.bkt[pos] = (unsigned short)b;
            }
            {
                int b = d4a.w >> 8;
                int pos = atomicAdd(&u.p.cur[b], 1);
                u.p.staged[pos] = make_int2(s4a.w | ((d4a.w & 255) << 17),
                                            __float_as_int(v4a.w));
                u.p.bkt[pos] = (unsigned short)b;
            }
        }
        if (hasB) {
            {
                int b = d4b.x >> 8;
                int pos = atomicAdd(&u.p.cur[b], 1);
                u.p.staged[pos] = make_int2(s4b.x | ((d4b.x & 255) << 17),
                                            __float_as_int(v4b.x));
                u.p.bkt[pos] = (unsigned short)b;
            }
            {
                int b = d4b.y >> 8;
                int pos = atomicAdd(&u.p.cur[b], 1);
                u.p.staged[pos] = make_int2(s4b.y | ((d4b.y & 255) << 17),
                                            __float_as_int(v4b.y));
                u.p.bkt[pos] = (unsigned short)b;
            }
            {
                int b = d4b.z >> 8;
                int pos = atomicAdd(&u.p.cur[b], 1);
                u.p.staged[pos] = make_int2(s4b.z | ((d4b.z & 255) << 17),
                                            __float_as_int(v4b.z));
                u.p.bkt[pos] = (unsigned short)b;
            }
            {
                int b = d4b.w >> 8;
                int pos = atomicAdd(&u.p.cur[b], 1);
                u.p.staged[pos] = make_int2(s4b.w | ((d4b.w & 255) << 17),
                                            __float_as_int(v4b.w));
                u.p.bkt[pos] = (unsigned short)b;
            }
        }
        __syncthreads();

        // writeout: contiguous per-bucket runs, coalesced from LDS
        for (int i = t; i < cnt; i += 512) {
            int bb = u.p.bkt[i];
            rec_out[u.p.gbase[bb] + (i - u.p.lofs[bb])] = u.p.staged[i];
        }
    } else {
        // ------------- gemm branch (verbatim R12/13: 8 waves x 16 rows) ----
        const int quad = lane >> 4;
        const int li   = lane & 15;
        const int rowBase = (blockIdx.x - NCHUNK) * 128;

        for (int i = t; i < D * D; i += 512) {
            int k = i >> 7, n = i & 127;
            u.wfrag[n >> 4][k >> 5][((k >> 3) & 3) * 16 + (n & 15)][k & 7] = f2bf(W[i]);
        }
        __syncthreads();

        f32x4 acc[8];
#pragma unroll
        for (int ct = 0; ct < 8; ++ct)
            acc[ct] = (f32x4){0.f, 0.f, 0.f, 0.f};

#pragma unroll
        for (int kt = 0; kt < 4; ++kt) {
            int row = rowBase + wave * 16 + li;
            if (row >= N_NODES) row = N_NODES - 1;           // clamp; store masked
            const float* xp = X + (size_t)row * D + kt * 32 + quad * 8;
            float4 f0 = ((const float4*)xp)[0];
            float4 f1 = ((const float4*)xp)[1];
            bf16x8 a;
            a[0] = (short)f2bf(f0.x); a[1] = (short)f2bf(f0.y);
            a[2] = (short)f2bf(f0.z); a[3] = (short)f2bf(f0.w);
            a[4] = (short)f2bf(f1.x); a[5] = (short)f2bf(f1.y);
            a[6] = (short)f2bf(f1.z); a[7] = (short)f2bf(f1.w);
#pragma unroll
            for (int ct = 0; ct < 8; ++ct) {
                bf16x8 b = *(const bf16x8*)&u.wfrag[ct][kt][lane][0];
                acc[ct] = __builtin_amdgcn_mfma_f32_16x16x32_bf16(a, b, acc[ct], 0, 0, 0);
            }
        }
        __syncthreads();

        unsigned short* sw = (unsigned short*)&u.stage[wave][0][0];  // 16 x 136 bf16
#pragma unroll
        for (int r = 0; r < 4; ++r) {
            int lrow = quad * 4 + r;
#pragma unroll
            for (int ct = 0; ct < 8; ++ct)
                sw[lrow * 136 + ct * 16 + li] = f2bf(acc[ct][r]);
        }
        for (int lrow = 0; lrow < 16; ++lrow) {
            int node = rowBase + wave * 16 + lrow;
            if (node < N_NODES)
                Sb[(size_t)node * 64 + lane] = ((unsigned*)sw)[lrow * 68 + lane];
        }
    }
}

// ---------------------------------------------------------------------------
// Fine sort within each 256-node bucket arena. Histogram pass DELETED —
// per-node counts come from partition's global atomics (nodecnt). Just:
// coalesced count read -> 256-scan -> vectorized scatter (2 records/load).
// Emits PACKED records src(17)|val-bf16(15).
// ---------------------------------------------------------------------------
__global__ __launch_bounds__(512) void fine_sort(
        const int2* __restrict__ rec,
        const int* __restrict__ gcnt,
        const int* __restrict__ nodecnt,
        int* __restrict__ offs,
        unsigned* __restrict__ sorted1) {
    __shared__ int fcur[256];
    __shared__ int fex[256];
    __shared__ int fwsum[4];

    const int c    = blockIdx.x;
    const int t    = threadIdx.x;
    const int lane = t & 63;
    const int beg  = c * CAPB;               // arena base (even)
    const int bcnt = gcnt[c];
    const int np   = bcnt >> 1;              // record pairs

    // scan per-node counts (coalesced 1 KB read; waves 0-3)
    if (t < 256) {
        int node = c * 256 + t;
        int hv   = (node < N_NODES) ? nodecnt[node] : 0;
        int incl = hv;
        for (int off = 1; off < 64; off <<= 1) {
            int uu = __shfl_up(incl, off);
            if (lane >= off) incl += uu;
        }
        if (lane == 63) fwsum[t >> 6] = incl;
        fex[t] = incl - hv;
    }
    __syncthreads();
    if (t < 256) {
        int pre = 0;
        for (int w = 0; w < (t >> 6); ++w) pre += fwsum[w];
        int excl = pre + fex[t];
        int node = c * 256 + t;
        if (node < N_NODES) offs[node] = beg + excl;
        fcur[t] = beg + excl;
    }
    __syncthreads();

    // scatter packed records, 2 per load
    for (int i = t; i < np; i += 512) {
        int4 q = ((const int4*)(rec + beg))[i];
        {
            int dl = (q.x >> 17) & 255;
            int p = atomicAdd(&fcur[dl], 1);
            unsigned vb = f2bf(__int_as_float(q.y));      // val >= 0 -> bit15==0
            sorted1[p] = (unsigned)(q.x & 0x1FFFF) | ((vb & 0x7FFFu) << 17);
        }
        {
            int dl = (q.z >> 17) & 255;
            int p = atomicAdd(&fcur[dl], 1);
            unsigned vb = f2bf(__int_as_float(q.w));
            sorted1[p] = (unsigned)(q.z & 0x1FFFF) | ((vb & 0x7FFFu) << 17);
        }
    }
    if (t == 0 && (bcnt & 1)) {
        int2 q = rec[beg + bcnt - 1];
        int dl = (q.x >> 17) & 255;
        int p = atomicAdd(&fcur[dl], 1);
        unsigned vb = f2bf(__int_as_float(q.y));
        sorted1[p] = (unsigned)(q.x & 0x1FFFF) | ((vb & 0x7FFFu) << 17);
    }
}

// ---------------------------------------------------------------------------
// Wave-per-node segmented reduce, QUARTER-wave record parallelism (verbatim
// R10/R12/R13; at its measured floor: FETCH ~351 MB across seven structural
// variants). Arena-aware ends: bucket-last node reads end = c*CAPB + cnt[c].
// Records 4 B packed: src = p & 0x1FFFF, val = (p>>17)<<16 as f32 bits.
// ---------------------------------------------------------------------------
#define FMA8(v, p) {                                                         \
    a0 += (v) * __uint_as_float((p).x << 16);                                \
    a1 += (v) * __uint_as_float((p).x & 0xFFFF0000u);                        \
    a2 += (v) * __uint_as_float((p).y << 16);                                \
    a3 += (v) * __uint_as_float((p).y & 0xFFFF0000u);                        \
    a4 += (v) * __uint_as_float((p).z << 16);                                \
    a5 += (v) * __uint_as_float((p).z & 0xFFFF0000u);                        \
    a6 += (v) * __uint_as_float((p).w << 16);                                \
    a7 += (v) * __uint_as_float((p).w & 0xFFFF0000u);                        \
}

__global__ __launch_bounds__(256) void reduce_segments(
        const unsigned* __restrict__ Sb,
        const unsigned* __restrict__ sorted,
        const int* __restrict__ offs,
        const int* __restrict__ gcnt,
        const float* __restrict__ bias,
        float* __restrict__ out) {
    const int lane = threadIdx.x & 63;
    const int node = (blockIdx.x * 256 + threadIdx.x) >> 6;
    if (node >= N_NODES) return;

    const int qr = lane >> 4;        // which record of the group of 4
    const int ql = lane & 15;        // lane within quarter: feats 8ql..8ql+7

    const int beg = offs[node];
    const bool blast = ((node & 255) == 255) || (node == N_NODES - 1);
    const int end = blast ? ((node >> 8) * CAPB + gcnt[node >> 8])
                          : offs[node + 1];

    float a0 = 0.f, a1 = 0.f, a2 = 0.f, a3 = 0.f;
    float a4 = 0.f, a5 = 0.f, a6 = 0.f, a7 = 0.f;

    for (int base = beg; base < end; base += 64) {
        const int m = min(64, end - base);
        unsigned rec = 0;
        if (base + lane < end) rec = sorted[base + lane];
        const int ng = (m + 3) >> 2;         // groups of 4 records

        int g = 0;
        for (; g + 4 <= ng; g += 4) {
            int i0 = 4 * (g + 0) + qr, i1 = 4 * (g + 1) + qr;
            int i2 = 4 * (g + 2) + qr, i3 = 4 * (g + 3) + qr;
            unsigned r0 = (unsigned)__shfl((int)rec, i0);
            unsigned r1 = (unsigned)__shfl((int)rec, i1);
            unsigned r2 = (unsigned)__shfl((int)rec, i2);
            unsigned r3 = (unsigned)__shfl((int)rec, i3);
            int s0 = r0 & 0x1FFFF, s1 = r1 & 0x1FFFF;
            int s2 = r2 & 0x1FFFF, s3 = r3 & 0x1FFFF;
            float v0 = __uint_as_float((r0 >> 17) << 16);
            float v1 = __uint_as_float((r1 >> 17) << 16);
            float v2 = __uint_as_float((r2 >> 17) << 16);
            float v3 = __uint_as_float((r3 >> 17) << 16);
            uint4 p0 = ((const uint4*)(Sb + (size_t)s0 * 64))[ql];
            uint4 p1 = ((const uint4*)(Sb + (size_t)s1 * 64))[ql];
            uint4 p2 = ((const uint4*)(Sb + (size_t)s2 * 64))[ql];
            uint4 p3 = ((const uint4*)(Sb + (size_t)s3 * 64))[ql];
            FMA8(v0, p0);
            FMA8(v1, p1);
            FMA8(v2, p2);
            FMA8(v3, p3);
        }
        for (; g < ng; ++g) {
            int i0 = 4 * g + qr;
            unsigned r0 = (unsigned)__shfl((int)rec, i0);
            int s0 = r0 & 0x1FFFF;
            float v0 = __uint_as_float((r0 >> 17) << 16);
            uint4 p0 = ((const uint4*)(Sb + (size_t)s0 * 64))[ql];
            FMA8(v0, p0);
        }
    }

    // combine the four quarters (feats 8ql..8ql+7 live in lanes ql, ql+16,
    // ql+32, ql+48)
    a0 += __shfl(a0, lane ^ 16); a1 += __shfl(a1, lane ^ 16);
    a2 += __shfl(a2, lane ^ 16); a3 += __shfl(a3, lane ^ 16);
    a4 += __shfl(a4, lane ^ 16); a5 += __shfl(a5, lane ^ 16);
    a6 += __shfl(a6, lane ^ 16); a7 += __shfl(a7, lane ^ 16);
    a0 += __shfl(a0, lane ^ 32); a1 += __shfl(a1, lane ^ 32);
    a2 += __shfl(a2, lane ^ 32); a3 += __shfl(a3, lane ^ 32);
    a4 += __shfl(a4, lane ^ 32); a5 += __shfl(a5, lane ^ 32);
    a6 += __shfl(a6, lane ^ 32); a7 += __shfl(a7, lane ^ 32);

    if (qr == 0) {
        float4 b0 = ((const float4*)bias)[2 * ql];
        float4 b1 = ((const float4*)bias)[2 * ql + 1];
        float4 r0 = make_float4(a0 + b0.x, a1 + b0.y, a2 + b0.z, a3 + b0.w);
        float4 r1 = make_float4(a4 + b1.x, a5 + b1.y, a6 + b1.z, a7 + b1.w);
        ((float4*)(out + (size_t)node * D))[2 * ql]     = r0;
        ((float4*)(out + (size_t)node * D))[2 * ql + 1] = r1;
    }
}

extern "C" void kernel_launch(void* const* d_in, const int* in_sizes, int n_in,
                              void* d_out, int out_size, void* d_ws, size_t ws_size,
                              hipStream_t stream) {
    const float* X    = (const float*)d_in[0];
    const int*   esrc = (const int*)  d_in[1];
    const int*   edst = (const int*)  d_in[2];
    const float* eval = (const float*)d_in[3];
    const float* W    = (const float*)d_in[4];
    const float* bias = (const float*)d_in[5];
    float* out = (float*)d_out;

    char* ws = (char*)d_ws;
    unsigned* SbU   = (unsigned*)(ws + OFF_SB);
    int2*     recs  = (int2*)    (ws + OFF_REC);
    unsigned* srt1  = (unsigned*)(ws + OFF_SORT2);
    int*      offs  = (int*)     (ws + OFF_OFFS);
    int*      ncnt  = (int*)     (ws + OFF_CNTS);          // nodecnt[N_NODES]
    int*      gcur  = ncnt + N_NODES;                      // gcur[K1C], contiguous

    // Zero per-node counts + per-bucket arena cursors in ONE memset
    hipMemsetAsync(ncnt, 0, (N_NODES + K1C) * 4, stream);

    // Fused: coarse partition (blocks 0..781) || gemm S = X@W (blocks 782..1563)
    part_and_gemm<<<NCHUNK + GEMMB, 512, 0, stream>>>(
        esrc, edst, eval, ncnt, gcur, recs, X, W, SbU);

    // Fine sort per bucket arena (scan of precomputed counts + scatter only)
    fine_sort<<<K1C, 512, 0, stream>>>(recs, gcur, ncnt, offs, srt1);

    // Segmented reduce: out[n] = bias + sum val * S[src]
    reduce_segments<<<(N_NODES + 3) / 4, 256, 0, stream>>>(
        SbU, srt1, offs, gcur, bias, out);
}

// Round 15
// 287.260 us; speedup vs baseline: 1.3594x; 1.3594x over previous
//
#include <hip/hip_runtime.h>

#define N_NODES 100000
#define N_EDGES 3200000
#define D 128

#define K1C    391        // coarse buckets: bucket = dst >> 8 (256 nodes each)
#define CHUNK  4096       // edges per partition block (multiple of 4)
#define NCHUNK 782        // ceil(N_EDGES / CHUNK); last block cnt=1024 (mult of 4)
#define GEMMB  782        // gemm tiles (128 rows each)
#define CAPB   8960       // arena capacity per bucket (mean 8192, +8.5 sigma; EVEN)

// ---------------------------------------------------------------------------
// Workspace layout (bytes). ws >= 78,000,512 proven. Bucket arenas (R10):
// bucket b's records live at [b*CAPB, b*CAPB + cnt[b]) — bases arithmetic.
// ---------------------------------------------------------------------------
static const size_t OFF_SB    = 0;           // S bf16 packed: N*64 uints = 25.6 MB
static const size_t OFF_REC   = 25600000;    // K1C*CAPB int2  = 28.03 MB
static const size_t OFF_SORT2 = 53626880;    // K1C*CAPB uint  = 14.01 MB
static const size_t OFF_OFFS  = 67640320;    // N ints
static const size_t OFF_GCUR  = 68040320;    // K1C ints (zeroed each launch)

typedef __attribute__((ext_vector_type(8))) short bf16x8;
typedef __attribute__((ext_vector_type(4))) float f32x4;

__device__ __forceinline__ unsigned short f2bf(float f) {
    unsigned u = __float_as_uint(f);
    return (unsigned short)((u + 0x7FFFu + ((u >> 16) & 1u)) >> 16);   // RNE
}

// ---------------------------------------------------------------------------
// FUSED kernel (512 threads): blocks [0,NCHUNK) run the LDS-staged coarse
// partition with VECTORIZED edge reads (int4/float4 = 4 edges per load);
// blocks [NCHUNK,NCHUNK+GEMMB) run the MFMA gemm (8 waves x 16 rows).
// R14 lesson reverted: NO per-edge global atomics (155 MB write-amp, +70 us)
// and NO register-carry (confounded in the same regression).
// ---------------------------------------------------------------------------
__global__ __launch_bounds__(512) void part_and_gemm(
        const int* __restrict__ esrc,
        const int* __restrict__ edst,
        const float* __restrict__ eval,
        int* __restrict__ gcursor,
        int2* __restrict__ rec_out,
        const float* __restrict__ X,
        const float* __restrict__ W,
        unsigned* __restrict__ Sb) {
    __shared__ __align__(16) union {
        unsigned short wfrag[8][4][64][8];   // gemm phase 1: 32 KB
        unsigned       stage[8][16][68];     // gemm phase 2: 34.8 KB
        struct {
            int2 staged[CHUNK];              // 32 KB
            unsigned short bkt[CHUNK];       // 8 KB
            int hist[K1C];
            int lofs[K1C];
            int gbase[K1C];
            int cur[K1C];
            int wsum[8];
        } p;                                 // partition: ~46.6 KB
    } u;

    const int t    = threadIdx.x;
    const int lane = t & 63;
    const int wave = t >> 6;

    if (blockIdx.x < NCHUNK) {
        // ------------- partition branch (vectorized loads) -----------------
        const int e0  = blockIdx.x * CHUNK;
        const int cnt = min(CHUNK, N_EDGES - e0);   // 4096 or 1024, %4 == 0
        const int nq  = cnt >> 2;

        for (int i = t; i < K1C; i += 512) u.p.hist[i] = 0;
        __syncthreads();

        // pass 1: histogram, int4 edst loads (4 edges per exposure)
        for (int i = t; i < nq; i += 512) {
            int4 d4 = ((const int4*)(edst + e0))[i];
            atomicAdd(&u.p.hist[d4.x >> 8], 1);
            atomicAdd(&u.p.hist[d4.y >> 8], 1);
            atomicAdd(&u.p.hist[d4.z >> 8], 1);
            atomicAdd(&u.p.hist[d4.w >> 8], 1);
        }
        __syncthreads();

        // scan K1C entries: per-wave shfl_up scan + cross-wave combine
        int hv   = (t < K1C) ? u.p.hist[t] : 0;
        int incl = hv;
        for (int off = 1; off < 64; off <<= 1) {
            int uu = __shfl_up(incl, off);
            if (lane >= off) incl += uu;
        }
        if (lane == 63) u.p.wsum[wave] = incl;
        __syncthreads();
        {
            int pre = 0;
            for (int w = 0; w < wave; ++w) pre += u.p.wsum[w];
            if (t < K1C) {
                int excl = pre + incl - hv;
                u.p.lofs[t]  = excl;
                u.p.cur[t]   = excl;
                u.p.gbase[t] = hv ? (t * CAPB + atomicAdd(&gcursor[t], hv)) : 0;
            }
        }
        __syncthreads();

        // pass 2: re-read edges vectorized (L2-hot), scatter into LDS staging
        for (int i = t; i < nq; i += 512) {
            int4   d4 = ((const int4*)(edst + e0))[i];
            int4   s4 = ((const int4*)(esrc + e0))[i];
            float4 v4 = ((const float4*)(eval + e0))[i];
            {
                int b = d4.x >> 8;
                int pos = atomicAdd(&u.p.cur[b], 1);
                u.p.staged[pos] = make_int2(s4.x | ((d4.x & 255) << 17),
                                            __float_as_int(v4.x));
                u.p.bkt[pos] = (unsigned short)b;
            }
            {
                int b = d4.y >> 8;
                int pos = atomicAdd(&u.p.cur[b], 1);
                u.p.staged[pos] = make_int2(s4.y | ((d4.y & 255) << 17),
                                            __float_as_int(v4.y));
                u.p.bkt[pos] = (unsigned short)b;
            }
            {
                int b = d4.z >> 8;
                int pos = atomicAdd(&u.p.cur[b], 1);
                u.p.staged[pos] = make_int2(s4.z | ((d4.z & 255) << 17),
                                            __float_as_int(v4.z));
                u.p.bkt[pos] = (unsigned short)b;
            }
            {
                int b = d4.w >> 8;
                int pos = atomicAdd(&u.p.cur[b], 1);
                u.p.staged[pos] = make_int2(s4.w | ((d4.w & 255) << 17),
                                            __float_as_int(v4.w));
                u.p.bkt[pos] = (unsigned short)b;
            }
        }
        __syncthreads();

        // writeout: contiguous per-bucket runs, coalesced from LDS
        for (int i = t; i < cnt; i += 512) {
            int bb = u.p.bkt[i];
            rec_out[u.p.gbase[bb] + (i - u.p.lofs[bb])] = u.p.staged[i];
        }
    } else {
        // ------------- gemm branch (verbatim: 8 waves x 16 rows) -----------
        const int quad = lane >> 4;
        const int li   = lane & 15;
        const int rowBase = (blockIdx.x - NCHUNK) * 128;

        for (int i = t; i < D * D; i += 512) {
            int k = i >> 7, n = i & 127;
            u.wfrag[n >> 4][k >> 5][((k >> 3) & 3) * 16 + (n & 15)][k & 7] = f2bf(W[i]);
        }
        __syncthreads();

        f32x4 acc[8];
#pragma unroll
        for (int ct = 0; ct < 8; ++ct)
            acc[ct] = (f32x4){0.f, 0.f, 0.f, 0.f};

#pragma unroll
        for (int kt = 0; kt < 4; ++kt) {
            int row = rowBase + wave * 16 + li;
            if (row >= N_NODES) row = N_NODES - 1;           // clamp; store masked
            const float* xp = X + (size_t)row * D + kt * 32 + quad * 8;
            float4 f0 = ((const float4*)xp)[0];
            float4 f1 = ((const float4*)xp)[1];
            bf16x8 a;
            a[0] = (short)f2bf(f0.x); a[1] = (short)f2bf(f0.y);
            a[2] = (short)f2bf(f0.z); a[3] = (short)f2bf(f0.w);
            a[4] = (short)f2bf(f1.x); a[5] = (short)f2bf(f1.y);
            a[6] = (short)f2bf(f1.z); a[7] = (short)f2bf(f1.w);
#pragma unroll
            for (int ct = 0; ct < 8; ++ct) {
                bf16x8 b = *(const bf16x8*)&u.wfrag[ct][kt][lane][0];
                acc[ct] = __builtin_amdgcn_mfma_f32_16x16x32_bf16(a, b, acc[ct], 0, 0, 0);
            }
        }
        __syncthreads();

        unsigned short* sw = (unsigned short*)&u.stage[wave][0][0];  // 16 x 136 bf16
#pragma unroll
        for (int r = 0; r < 4; ++r) {
            int lrow = quad * 4 + r;
#pragma unroll
            for (int ct = 0; ct < 8; ++ct)
                sw[lrow * 136 + ct * 16 + li] = f2bf(acc[ct][r]);
        }
        for (int lrow = 0; lrow < 16; ++lrow) {
            int node = rowBase + wave * 16 + lrow;
            if (node < N_NODES)
                Sb[(size_t)node * 64 + lane] = ((unsigned*)sw)[lrow * 68 + lane];
        }
    }
}

// ---------------------------------------------------------------------------
// Fine sort within each 256-node bucket arena (standalone, 2.2 KB LDS, high
// occupancy). VECTORIZED: int4 = 2 records per load in both passes; scalar
// tail (<=1 record) by t==0. Emits PACKED records src(17)|val-bf16(15).
// ---------------------------------------------------------------------------
__global__ __launch_bounds__(512) void fine_sort(
        const int2* __restrict__ rec,
        const int* __restrict__ gcnt,
        int* __restrict__ offs,
        unsigned* __restrict__ sorted1) {
    __shared__ int fh[256];
    __shared__ int fcur[256];
    __shared__ int fwsum[4];

    const int c    = blockIdx.x;
    const int t    = threadIdx.x;
    const int lane = t & 63;
    const int beg  = c * CAPB;               // arena base (even)
    const int bcnt = gcnt[c];
    const int np   = bcnt >> 1;              // record pairs

    if (t < 256) fh[t] = 0;
    __syncthreads();

    // pass 1: dst-local histogram, 2 records per load
    for (int i = t; i < np; i += 512) {
        int4 q = ((const int4*)(rec + beg))[i];
        atomicAdd(&fh[(q.x >> 17) & 255], 1);
        atomicAdd(&fh[(q.z >> 17) & 255], 1);
    }
    if (t == 0 && (bcnt & 1))
        atomicAdd(&fh[(rec[beg + bcnt - 1].x >> 17) & 255], 1);
    __syncthreads();

    // inclusive scan of fh[0..255]: waves 0-3 (t<256) + combine
    if (t < 256) {
        int hv   = fh[t];
        int incl = hv;
        for (int off = 1; off < 64; off <<= 1) {
            int uu = __shfl_up(incl, off);
            if (lane >= off) incl += uu;
        }
        if (lane == 63) fwsum[t >> 6] = incl;
        fh[t] = incl - hv;                   // stash per-thread exclusive part
    }
    __syncthreads();
    if (t < 256) {
        int pre = 0;
        for (int w = 0; w < (t >> 6); ++w) pre += fwsum[w];
        int excl = pre + fh[t];
        int node = c * 256 + t;
        if (node < N_NODES) offs[node] = beg + excl;
        fcur[t] = beg + excl;
    }
    __syncthreads();

    // pass 2: scatter packed records, 2 per load
    for (int i = t; i < np; i += 512) {
        int4 q = ((const int4*)(rec + beg))[i];
        {
            int dl = (q.x >> 17) & 255;
            int p = atomicAdd(&fcur[dl], 1);
            unsigned vb = f2bf(__int_as_float(q.y));      // val >= 0 -> bit15==0
            sorted1[p] = (unsigned)(q.x & 0x1FFFF) | ((vb & 0x7FFFu) << 17);
        }
        {
            int dl = (q.z >> 17) & 255;
            int p = atomicAdd(&fcur[dl], 1);
            unsigned vb = f2bf(__int_as_float(q.w));
            sorted1[p] = (unsigned)(q.z & 0x1FFFF) | ((vb & 0x7FFFu) << 17);
        }
    }
    if (t == 0 && (bcnt & 1)) {
        int2 q = rec[beg + bcnt - 1];
        int dl = (q.x >> 17) & 255;
        int p = atomicAdd(&fcur[dl], 1);
        unsigned vb = f2bf(__int_as_float(q.y));
        sorted1[p] = (unsigned)(q.x & 0x1FFFF) | ((vb & 0x7FFFu) << 17);
    }
}

// ---------------------------------------------------------------------------
// Wave-per-node segmented reduce, QUARTER-wave record parallelism (at its
// measured floor: FETCH ~351 MB / ~105 us across seven structural variants).
// Arena-aware ends: bucket-last node reads end = c*CAPB + cnt[c].
// Records 4 B packed: src = p & 0x1FFFF, val = (p>>17)<<16 as f32 bits.
// ---------------------------------------------------------------------------
#define FMA8(v, p) {                                                         \
    a0 += (v) * __uint_as_float((p).x << 16);                                \
    a1 += (v) * __uint_as_float((p).x & 0xFFFF0000u);                        \
    a2 += (v) * __uint_as_float((p).y << 16);                                \
    a3 += (v) * __uint_as_float((p).y & 0xFFFF0000u);                        \
    a4 += (v) * __uint_as_float((p).z << 16);                                \
    a5 += (v) * __uint_as_float((p).z & 0xFFFF0000u);                        \
    a6 += (v) * __uint_as_float((p).w << 16);                                \
    a7 += (v) * __uint_as_float((p).w & 0xFFFF0000u);                        \
}

__global__ __launch_bounds__(256) void reduce_segments(
        const unsigned* __restrict__ Sb,
        const unsigned* __restrict__ sorted,
        const int* __restrict__ offs,
        const int* __restrict__ gcnt,
        const float* __restrict__ bias,
        float* __restrict__ out) {
    const int lane = threadIdx.x & 63;
    const int node = (blockIdx.x * 256 + threadIdx.x) >> 6;
    if (node >= N_NODES) return;

    const int qr = lane >> 4;        // which record of the group of 4
    const int ql = lane & 15;        // lane within quarter: feats 8ql..8ql+7

    const int beg = offs[node];
    const bool blast = ((node & 255) == 255) || (node == N_NODES - 1);
    const int end = blast ? ((node >> 8) * CAPB + gcnt[node >> 8])
                          : offs[node + 1];

    float a0 = 0.f, a1 = 0.f, a2 = 0.f, a3 = 0.f;
    float a4 = 0.f, a5 = 0.f, a6 = 0.f, a7 = 0.f;

    for (int base = beg; base < end; base += 64) {
        const int m = min(64, end - base);
        unsigned rec = 0;
        if (base + lane < end) rec = sorted[base + lane];
        const int ng = (m + 3) >> 2;         // groups of 4 records

        int g = 0;
        for (; g + 4 <= ng; g += 4) {
            int i0 = 4 * (g + 0) + qr, i1 = 4 * (g + 1) + qr;
            int i2 = 4 * (g + 2) + qr, i3 = 4 * (g + 3) + qr;
            unsigned r0 = (unsigned)__shfl((int)rec, i0);
            unsigned r1 = (unsigned)__shfl((int)rec, i1);
            unsigned r2 = (unsigned)__shfl((int)rec, i2);
            unsigned r3 = (unsigned)__shfl((int)rec, i3);
            int s0 = r0 & 0x1FFFF, s1 = r1 & 0x1FFFF;
            int s2 = r2 & 0x1FFFF, s3 = r3 & 0x1FFFF;
            float v0 = __uint_as_float((r0 >> 17) << 16);
            float v1 = __uint_as_float((r1 >> 17) << 16);
            float v2 = __uint_as_float((r2 >> 17) << 16);
            float v3 = __uint_as_float((r3 >> 17) << 16);
            uint4 p0 = ((const uint4*)(Sb + (size_t)s0 * 64))[ql];
            uint4 p1 = ((const uint4*)(Sb + (size_t)s1 * 64))[ql];
            uint4 p2 = ((const uint4*)(Sb + (size_t)s2 * 64))[ql];
            uint4 p3 = ((const uint4*)(Sb + (size_t)s3 * 64))[ql];
            FMA8(v0, p0);
            FMA8(v1, p1);
            FMA8(v2, p2);
            FMA8(v3, p3);
        }
        for (; g < ng; ++g) {
            int i0 = 4 * g + qr;
            unsigned r0 = (unsigned)__shfl((int)rec, i0);
            int s0 = r0 & 0x1FFFF;
            float v0 = __uint_as_float((r0 >> 17) << 16);
            uint4 p0 = ((const uint4*)(Sb + (size_t)s0 * 64))[ql];
            FMA8(v0, p0);
        }
    }

    // combine the four quarters (feats 8ql..8ql+7 live in lanes ql, ql+16,
    // ql+32, ql+48)
    a0 += __shfl(a0, lane ^ 16); a1 += __shfl(a1, lane ^ 16);
    a2 += __shfl(a2, lane ^ 16); a3 += __shfl(a3, lane ^ 16);
    a4 += __shfl(a4, lane ^ 16); a5 += __shfl(a5, lane ^ 16);
    a6 += __shfl(a6, lane ^ 16); a7 += __shfl(a7, lane ^ 16);
    a0 += __shfl(a0, lane ^ 32); a1 += __shfl(a1, lane ^ 32);
    a2 += __shfl(a2, lane ^ 32); a3 += __shfl(a3, lane ^ 32);
    a4 += __shfl(a4, lane ^ 32); a5 += __shfl(a5, lane ^ 32);
    a6 += __shfl(a6, lane ^ 32); a7 += __shfl(a7, lane ^ 32);

    if (qr == 0) {
        float4 b0 = ((const float4*)bias)[2 * ql];
        float4 b1 = ((const float4*)bias)[2 * ql + 1];
        float4 r0 = make_float4(a0 + b0.x, a1 + b0.y, a2 + b0.z, a3 + b0.w);
        float4 r1 = make_float4(a4 + b1.x, a5 + b1.y, a6 + b1.z, a7 + b1.w);
        ((float4*)(out + (size_t)node * D))[2 * ql]     = r0;
        ((float4*)(out + (size_t)node * D))[2 * ql + 1] = r1;
    }
}

extern "C" void kernel_launch(void* const* d_in, const int* in_sizes, int n_in,
                              void* d_out, int out_size, void* d_ws, size_t ws_size,
                              hipStream_t stream) {
    const float* X    = (const float*)d_in[0];
    const int*   esrc = (const int*)  d_in[1];
    const int*   edst = (const int*)  d_in[2];
    const float* eval = (const float*)d_in[3];
    const float* W    = (const float*)d_in[4];
    const float* bias = (const float*)d_in[5];
    float* out = (float*)d_out;

    char* ws = (char*)d_ws;
    unsigned* SbU   = (unsigned*)(ws + OFF_SB);
    int2*     recs  = (int2*)    (ws + OFF_REC);
    unsigned* srt1  = (unsigned*)(ws + OFF_SORT2);
    int*      offs  = (int*)     (ws + OFF_OFFS);
    int*      gcur  = (int*)     (ws + OFF_GCUR);

    // Zero per-bucket arena cursors (bucket bases are arithmetic: b*CAPB)
    hipMemsetAsync(gcur, 0, K1C * 4, stream);

    // Fused: coarse partition (blocks 0..781) || gemm S = X@W (blocks 782..1563)
    part_and_gemm<<<NCHUNK + GEMMB, 512, 0, stream>>>(
        esrc, edst, eval, gcur, recs, X, W, SbU);

    // Fine sort per bucket arena (standalone, high occupancy, vectorized)
    fine_sort<<<K1C, 512, 0, stream>>>(recs, gcur, offs, srt1);

    // Segmented reduce: out[n] = bias + sum val * S[src]
    reduce_segments<<<(N_NODES + 3) / 4, 256, 0, stream>>>(
        SbU, srt1, offs, gcur, bias, out);
}